// Round 3
// baseline (454.035 us; speedup 1.0000x reference)
//
#include <hip/hip_runtime.h>
#include <hip/hip_bf16.h>

// ArcFace head: out[b,c] = S * margin(clip(dot(f_b,w_c)/(|f_b||w_c|)))
// Fused single kernel: fp16 MFMA GEMM (fp32 accum) on raw values; per-row
// fp32 sum-of-squares accumulated during staging; normalize+clip+margin+scale
// in epilogue.
//
// R3 = R2 with types fixed: __builtin_amdgcn_cvt_pkrtz and the f16 MFMA
// builtins use __fp16 ext-vectors (clang 'h'), not _Float16.
// R2 changes vs R1: (1) fp16 + v_cvt_pkrtz packed convert, (2) LDS k-stride
// padded 32->40 halves (80B = 5*16B: b128-aligned, conflict-free fragment
// reads), (3) XCD swizzle: 4 same-n blocks -> same XCD for weight L2 reuse,
// (4) software pipeline: next iteration's global loads before this MFMA set.

typedef __attribute__((ext_vector_type(8))) __fp16 half8;
typedef __attribute__((ext_vector_type(2))) __fp16 half2v;
typedef __attribute__((ext_vector_type(4))) float f32x4;

#define TH_CONST  (-0.8775825618903728f)   // cos(pi - 0.5)
#define MM_CONST  (0.23971276930210156f)   // sin(pi - 0.5) * 0.5
#define M_MARGIN  0.5f
#define S_SCALE   64.0f

#define BM 128
#define BN 128
#define BK 32
#define KD 512
#define LDK 40   // padded k-stride in halves (80 B = 5 * 16 B)

union H8 { half2v h2[4]; half8 h8; };

__device__ __forceinline__ void cvt16(H8& lo, H8& hi,
                                      const float4& x0, const float4& x1,
                                      const float4& x2, const float4& x3) {
    lo.h2[0] = __builtin_amdgcn_cvt_pkrtz(x0.x, x0.y);
    lo.h2[1] = __builtin_amdgcn_cvt_pkrtz(x0.z, x0.w);
    lo.h2[2] = __builtin_amdgcn_cvt_pkrtz(x1.x, x1.y);
    lo.h2[3] = __builtin_amdgcn_cvt_pkrtz(x1.z, x1.w);
    hi.h2[0] = __builtin_amdgcn_cvt_pkrtz(x2.x, x2.y);
    hi.h2[1] = __builtin_amdgcn_cvt_pkrtz(x2.z, x2.w);
    hi.h2[2] = __builtin_amdgcn_cvt_pkrtz(x3.x, x3.y);
    hi.h2[3] = __builtin_amdgcn_cvt_pkrtz(x3.z, x3.w);
}

__device__ __forceinline__ float sq16(const float4& x0, const float4& x1,
                                      const float4& x2, const float4& x3) {
    return x0.x*x0.x + x0.y*x0.y + x0.z*x0.z + x0.w*x0.w
         + x1.x*x1.x + x1.y*x1.y + x1.z*x1.z + x1.w*x1.w
         + x2.x*x2.x + x2.y*x2.y + x2.z*x2.z + x2.w*x2.w
         + x3.x*x3.x + x3.y*x3.y + x3.z*x3.z + x3.w*x3.w;
}

__global__ __launch_bounds__(256, 2)
void arcface_kernel(const float* __restrict__ F,     // [512][512]
                    const int*   __restrict__ labels,// [512]
                    const float* __restrict__ W,     // [C][512]
                    float*       __restrict__ Out,   // [512][C]
                    const int C, const int MB, const int NB)
{
    __shared__ __fp16 As[BM][LDK];
    __shared__ __fp16 Bs[BN][LDK];
    __shared__ float normF[BM];
    __shared__ float normW[BN];
    __shared__ int   Ls[BM];

    // ---- XCD swizzle: same-n blocks get IDs == same (mod 8) -> same XCD ----
    const int id = blockIdx.x;
    const int group = 8 * MB;
    const int full  = (NB / 8) * group;
    int m_idx, n_idx;
    if (id < full) {
        const int chunk = id / group, pos = id % group;
        n_idx = chunk * 8 + (pos & 7);
        m_idx = pos >> 3;
    } else {
        const int tail = NB - (NB / 8) * 8;     // >0 whenever this branch taken
        const int r2 = id - full;
        n_idx = (NB / 8) * 8 + (r2 % tail);
        m_idx = r2 / tail;
    }
    const int m_base = m_idx * BM;
    const int n_base = n_idx * BN;

    const int t = threadIdx.x;
    if (t < BM) Ls[t] = labels[m_base + t];

    // staging: thread t covers row r (0..127), k-half h (16 floats per iter)
    const int r = t >> 1;
    const int h = t & 1;

    const int lane = t & 63;
    const int wave = t >> 6;
    const int wm = (wave >> 1) * 64;
    const int wn = (wave & 1) * 64;
    const int quad = lane >> 4;
    const int lcol = lane & 15;

    f32x4 acc[4][4];
    #pragma unroll
    for (int i = 0; i < 4; ++i)
        #pragma unroll
        for (int j = 0; j < 4; ++j)
            acc[i][j] = (f32x4){0.f, 0.f, 0.f, 0.f};

    const int cls = n_base + r;
    const bool cvalid = (cls < C);

    const float* Arow = F + (size_t)(m_base + r) * KD + h * 16;
    const float* Wrow = W + (size_t)(cvalid ? cls : 0) * KD + h * 16;

    float sF = 0.f, sW = 0.f;

    // ---- prologue: load iteration 0 ----
    float4 a0, a1, a2, a3, w0, w1, w2, w3;
    {
        const float4* ap = (const float4*)(Arow);
        const float4* wp = (const float4*)(Wrow);
        a0 = ap[0]; a1 = ap[1]; a2 = ap[2]; a3 = ap[3];
        if (cvalid) { w0 = wp[0]; w1 = wp[1]; w2 = wp[2]; w3 = wp[3]; }
        else { w0 = make_float4(0.f,0.f,0.f,0.f); w1 = w0; w2 = w0; w3 = w0; }
    }

    for (int kt = 0; kt < KD / BK; ++kt) {
        // ---- consume current regs: sumsq + packed fp16 convert ----
        sF += sq16(a0, a1, a2, a3);
        sW += sq16(w0, w1, w2, w3);
        H8 ua0, ua1, ub0, ub1;
        cvt16(ua0, ua1, a0, a1, a2, a3);
        cvt16(ub0, ub1, w0, w1, w2, w3);

        __syncthreads();   // previous iteration's fragment reads done
        *(half8*)&As[r][h*16]     = ua0.h8;
        *(half8*)&As[r][h*16 + 8] = ua1.h8;
        *(half8*)&Bs[r][h*16]     = ub0.h8;
        *(half8*)&Bs[r][h*16 + 8] = ub1.h8;
        __syncthreads();   // tiles visible

        // ---- prefetch next iteration (in flight across the MFMAs below) ----
        if (kt + 1 < KD / BK) {
            const float4* ap = (const float4*)(Arow + (kt + 1) * BK);
            const float4* wp = (const float4*)(Wrow + (kt + 1) * BK);
            a0 = ap[0]; a1 = ap[1]; a2 = ap[2]; a3 = ap[3];
            if (cvalid) { w0 = wp[0]; w1 = wp[1]; w2 = wp[2]; w3 = wp[3]; }
        }

        // ---- fragments + MFMA (A[m=lane&15][k=quad*8+j], same for B) ----
        half8 af[4], bfr[4];
        #pragma unroll
        for (int i = 0; i < 4; ++i) {
            af[i]  = *(const half8*)&As[wm + i*16 + lcol][quad*8];
            bfr[i] = *(const half8*)&Bs[wn + i*16 + lcol][quad*8];
        }
        #pragma unroll
        for (int i = 0; i < 4; ++i)
            #pragma unroll
            for (int j = 0; j < 4; ++j)
                acc[i][j] = __builtin_amdgcn_mfma_f32_16x16x32_f16(
                                af[i], bfr[j], acc[i][j], 0, 0, 0);
    }

    // ---- finish norms: (h=0,h=1) are adjacent lanes ----
    sF += __shfl_xor(sF, 1);
    sW += __shfl_xor(sW, 1);
    if (h == 0) {
        normF[r] = 1.0f / sqrtf(sF + 1e-12f);
        normW[r] = 1.0f / sqrtf(sW + 1e-12f);
    }
    __syncthreads();

    // ---- epilogue: C/D layout col=lane&15, row=quad*4+reg ----
    #pragma unroll
    for (int mi = 0; mi < 4; ++mi) {
        const int rl_base = wm + mi*16 + quad*4;
        #pragma unroll
        for (int rg = 0; rg < 4; ++rg) {
            const int rl = rl_base + rg;
            const float invf = normF[rl];
            const int lbl = Ls[rl];
            float* orow = Out + (size_t)(m_base + rl) * C;
            #pragma unroll
            for (int ni = 0; ni < 4; ++ni) {
                const int cl = wn + ni*16 + lcol;
                const int gcol = n_base + cl;
                if (gcol < C) {
                    float v = acc[mi][ni][rg] * invf * normW[cl];
                    v = fminf(1.0f, fmaxf(-1.0f, v));
                    if (gcol == lbl) {
                        v = (v > TH_CONST) ? cosf(acosf(v) + M_MARGIN)
                                           : (v - MM_CONST);
                    }
                    orow[gcol] = S_SCALE * v;
                }
            }
        }
    }
}

extern "C" void kernel_launch(void* const* d_in, const int* in_sizes, int n_in,
                              void* d_out, int out_size, void* d_ws, size_t ws_size,
                              hipStream_t stream) {
    const float* F      = (const float*)d_in[0];
    const int*   labels = (const int*)d_in[1];
    const float* W      = (const float*)d_in[2];
    float*       Out    = (float*)d_out;

    const int B = in_sizes[1];          // 512
    const int C = in_sizes[2] / KD;     // 100000
    const int MB = B / BM;              // 4
    const int NB = (C + BN - 1) / BN;   // 782

    arcface_kernel<<<dim3(MB * NB), dim3(256), 0, stream>>>(F, labels, W, Out, C, MB, NB);
}